// Round 1
// baseline (111.454 us; speedup 1.0000x reference)
//
#include <hip/hip_runtime.h>

// YOLO layer loss. B=32, H=W=32, A=9, C=80, T=50, NET=512.
// One thread per (b,h,w,a) cell. 36 blocks of 256 threads per batch image.

constexpr int NT = 50;      // true boxes
constexpr int BPB = 36;     // blocks per batch (32*32*9 / 256)

__global__ __launch_bounds__(256) void yolo_loss_kernel(
    const float* __restrict__ y_pred,     // (B,H,W,765) == (B,H,W,A,85) flat
    const float* __restrict__ y_true,     // (B,H,W,A,85)
    const float* __restrict__ true_boxes, // (B,50,4)
    const float* __restrict__ anchors,    // (9,2)
    float* __restrict__ out)              // (B,)
{
    __shared__ float s_tminx[NT], s_tminy[NT], s_tmaxx[NT], s_tmaxy[NT], s_tarea[NT];
    __shared__ float s_anch[18];
    __shared__ float s_red[4];

    const int b     = blockIdx.x / BPB;
    const int local = (blockIdx.x % BPB) * 256 + threadIdx.x;

    // Stage per-batch true-box geometry into LDS (broadcast reads later).
    if (threadIdx.x < NT) {
        const float* tb = true_boxes + ((size_t)b * NT + threadIdx.x) * 4;
        float tx = tb[0] * (1.0f / 32.0f);
        float ty = tb[1] * (1.0f / 32.0f);
        float tw = tb[2] * (1.0f / 512.0f);
        float th = tb[3] * (1.0f / 512.0f);
        s_tminx[threadIdx.x] = tx - tw * 0.5f;
        s_tmaxx[threadIdx.x] = tx + tw * 0.5f;
        s_tminy[threadIdx.x] = ty - th * 0.5f;
        s_tmaxy[threadIdx.x] = ty + th * 0.5f;
        s_tarea[threadIdx.x] = tw * th;
    }
    if (threadIdx.x < 18) s_anch[threadIdx.x] = anchors[threadIdx.x];
    __syncthreads();

    const int a = local % 9;
    const int w = (local / 9) % 32;
    const int h = local / 288;

    const size_t cell = (size_t)b * 9216 + (size_t)local;
    const float* p = y_pred + cell * 85;
    const float* t = y_true + cell * 85;

    const float p0 = p[0], p1 = p[1], p2 = p[2], p3 = p[3], p4 = p[4];
    const float t0 = t[0], t1 = t[1], t2 = t[2], t3 = t[3], t4 = t[4];

    const float aw = s_anch[a * 2 + 0];
    const float ah = s_anch[a * 2 + 1];

    const float sig0  = 1.0f / (1.0f + __expf(-p0));
    const float sig1  = 1.0f / (1.0f + __expf(-p1));
    const float predx = (float)w + sig0;
    const float predy = (float)h + sig1;
    const float pconf = 1.0f / (1.0f + __expf(-p4));

    // ---- IoU ignore flag: best_iou >= 0.5  <=>  exists t: 2*inter >= union ----
    const float px = predx * (1.0f / 32.0f);
    const float py = predy * (1.0f / 32.0f);
    const float pw = __expf(p2) * aw * (1.0f / 512.0f);
    const float ph = __expf(p3) * ah * (1.0f / 512.0f);
    const float pminx = px - pw * 0.5f, pmaxx = px + pw * 0.5f;
    const float pminy = py - ph * 0.5f, pmaxy = py + ph * 0.5f;
    const float parea = pw * ph;

    bool ignore = false;
    #pragma unroll 10
    for (int i = 0; i < NT; ++i) {
        float iw = fminf(pmaxx, s_tmaxx[i]) - fmaxf(pminx, s_tminx[i]);
        float ih = fminf(pmaxy, s_tmaxy[i]) - fmaxf(pminy, s_tminy[i]);
        iw = fmaxf(iw, 0.0f);
        ih = fmaxf(ih, 0.0f);
        float inter = iw * ih;
        float uni   = parea + s_tarea[i] - inter;
        ignore = ignore || (2.0f * inter >= uni);
    }

    // ---- Classes: fused argmax(true) capture of pred + online logsumexp(pred).
    // 4 independent accumulator streams to break the exp dependency chain.
    float tm[4], pa[4], mm[4], ss[4];
    #pragma unroll
    for (int k = 0; k < 4; ++k) { tm[k] = -1e30f; pa[k] = 0.0f; mm[k] = -1e30f; ss[k] = 0.0f; }

    #pragma unroll 4
    for (int j = 0; j < 20; ++j) {
        #pragma unroll
        for (int k = 0; k < 4; ++k) {
            const int i = j * 4 + k;
            const float tc = t[5 + i];
            const float pc = p[5 + i];
            const bool upd = tc > tm[k];
            tm[k] = upd ? tc : tm[k];
            pa[k] = upd ? pc : pa[k];
            const float mn = fmaxf(mm[k], pc);
            ss[k] = ss[k] * __expf(mm[k] - mn) + __expf(pc - mn);
            mm[k] = mn;
        }
    }
    // combine streams (strict > keeps lowest stream index on impossible ties)
    float tmax = tm[0], p_at = pa[0];
    #pragma unroll
    for (int k = 1; k < 4; ++k) {
        const bool upd = tm[k] > tmax;
        tmax = upd ? tm[k] : tmax;
        p_at = upd ? pa[k] : p_at;
    }
    const float m = fmaxf(fmaxf(mm[0], mm[1]), fmaxf(mm[2], mm[3]));
    const float s = ss[0] * __expf(mm[0] - m) + ss[1] * __expf(mm[1] - m) +
                    ss[2] * __expf(mm[2] - m) + ss[3] * __expf(mm[3] - m);
    const float ce = (m + __logf(s)) - p_at;   // logsumexp - pred[true_class]

    // ---- deltas ----
    const float om = t4;                                  // object_mask == true_conf
    const float ew = __expf(t2) * aw * (1.0f / 512.0f);
    const float eh = __expf(t3) * ah * (1.0f / 512.0f);
    const float whs = 2.0f - ew * eh;

    const float xyd0 = om * (predx - t0) * whs;
    const float xyd1 = om * (predy - t1) * whs;
    const float whd0 = om * (p2 - t2) * whs;
    const float whd1 = om * (p3 - t3) * whs;
    const float noobj = ignore ? 0.0f : pconf;
    const float cd = om * (pconf - t4) * 5.0f + (1.0f - om) * noobj;

    float partial = xyd0 * xyd0 + xyd1 * xyd1 + whd0 * whd0 + whd1 * whd1 +
                    cd * cd + om * ce;

    // ---- block reduction + one atomic per block ----
    #pragma unroll
    for (int off = 32; off > 0; off >>= 1)
        partial += __shfl_down(partial, off);

    const int wid  = threadIdx.x >> 6;
    const int lane = threadIdx.x & 63;
    if (lane == 0) s_red[wid] = partial;
    __syncthreads();
    if (threadIdx.x == 0)
        atomicAdd(&out[b], s_red[0] + s_red[1] + s_red[2] + s_red[3]);
}

extern "C" void kernel_launch(void* const* d_in, const int* in_sizes, int n_in,
                              void* d_out, int out_size, void* d_ws, size_t ws_size,
                              hipStream_t stream) {
    // setup_inputs order: input_image (unused), y_pred, y_true, true_boxes, anchors
    const float* y_pred     = (const float*)d_in[1];
    const float* y_true     = (const float*)d_in[2];
    const float* true_boxes = (const float*)d_in[3];
    const float* anchors    = (const float*)d_in[4];
    float* out = (float*)d_out;

    hipMemsetAsync(d_out, 0, (size_t)out_size * sizeof(float), stream);

    dim3 grid(32 * BPB);   // 1152 blocks: 36 per batch image
    yolo_loss_kernel<<<grid, 256, 0, stream>>>(y_pred, y_true, true_boxes, anchors, out);
}

// Round 2
// 71.690 us; speedup vs baseline: 1.5547x; 1.5547x over previous
//
#include <hip/hip_runtime.h>

// YOLO loss. B=32, H=W=32, A=9, C=80, T=50, NET=512.
// 4 lanes cooperate per cell (component-interleaved loads: lane s reads
// floats idx = 4j+s). Block = 256 threads = 64 cells. Grid = 4608 blocks.

constexpr int NT = 50;

__global__ __launch_bounds__(256) void yolo_loss_kernel(
    const float* __restrict__ y_pred,     // (B,H,W,A,85) flat
    const float* __restrict__ y_true,     // (B,H,W,A,85)
    const float* __restrict__ true_boxes, // (B,50,4)
    const float* __restrict__ anchors,    // (9,2)
    float* __restrict__ out)              // (B,)
{
    __shared__ float s_tminx[NT], s_tminy[NT], s_tmaxx[NT], s_tmaxy[NT], s_tarea[NT];
    __shared__ float s_anch[18];
    __shared__ float s_red[4];

    const int cell0 = blockIdx.x * 64;       // 64 cells per block, all same batch b
    const int b     = cell0 / 9216;

    if (threadIdx.x < NT) {
        const float* tb = true_boxes + ((size_t)b * NT + threadIdx.x) * 4;
        float tx = tb[0] * (1.0f / 32.0f);
        float ty = tb[1] * (1.0f / 32.0f);
        float tw = tb[2] * (1.0f / 512.0f);
        float th = tb[3] * (1.0f / 512.0f);
        s_tminx[threadIdx.x] = tx - tw * 0.5f;
        s_tmaxx[threadIdx.x] = tx + tw * 0.5f;
        s_tminy[threadIdx.x] = ty - th * 0.5f;
        s_tmaxy[threadIdx.x] = ty + th * 0.5f;
        s_tarea[threadIdx.x] = tw * th;
    }
    if (threadIdx.x < 18) s_anch[threadIdx.x] = anchors[threadIdx.x];
    __syncthreads();

    const int s    = threadIdx.x & 3;        // slice within cell group
    const int g    = threadIdx.x >> 2;       // cell group within block: 0..63
    const int lane = threadIdx.x & 63;
    const int gb   = lane & ~3;              // group base lane in wave

    const int cell  = cell0 + g;
    const int local = cell - b * 9216;
    const int a = local % 9;
    const int w = (local / 9) % 32;
    const int h = local / 288;

    const size_t base = (size_t)cell * 85 + s;
    const float* P = y_pred + base;
    const float* T = y_true + base;

    // ---- coalesced interleaved loads: lane s owns floats idx = 4j+s ----
    float pv[21], tv[21];
    #pragma unroll
    for (int j = 0; j < 21; ++j) pv[j] = P[4 * j];
    #pragma unroll
    for (int j = 0; j < 21; ++j) tv[j] = T[4 * j];
    float p84 = 0.0f, t84 = 0.0f;
    if (s == 0) { p84 = P[84]; t84 = T[84]; }   // idx 84 (class 79), s=0 only

    // ---- gather box fields via shuffles (idx n lives on lane gb+n, v[0];
    //      idx 4 lives on lane gb+0, v[1]) ----
    const float p0 = __shfl(pv[0], gb + 0);
    const float p1 = __shfl(pv[0], gb + 1);
    const float p2 = __shfl(pv[0], gb + 2);
    const float p3 = __shfl(pv[0], gb + 3);
    const float p4 = __shfl(pv[1], gb + 0);
    const float t0 = __shfl(tv[0], gb + 0);
    const float t1 = __shfl(tv[0], gb + 1);
    const float t2 = __shfl(tv[0], gb + 2);
    const float t3 = __shfl(tv[0], gb + 3);
    const float t4 = __shfl(tv[1], gb + 0);

    const float aw = s_anch[a * 2 + 0];
    const float ah = s_anch[a * 2 + 1];

    // ---- geometry (computed redundantly on all 4 lanes) ----
    const float sig0  = 1.0f / (1.0f + __expf(-p0));
    const float sig1  = 1.0f / (1.0f + __expf(-p1));
    const float predx = (float)w + sig0;
    const float predy = (float)h + sig1;
    const float pconf = 1.0f / (1.0f + __expf(-p4));

    const float px = predx * (1.0f / 32.0f);
    const float py = predy * (1.0f / 32.0f);
    const float pw = __expf(p2) * aw * (1.0f / 512.0f);
    const float ph = __expf(p3) * ah * (1.0f / 512.0f);
    const float pminx = px - pw * 0.5f, pmaxx = px + pw * 0.5f;
    const float pminy = py - ph * 0.5f, pmaxy = py + ph * 0.5f;
    const float parea = pw * ph;

    // ---- IoU ignore flag, split 12-13 boxes per lane ----
    // best_iou >= 0.5  <=>  exists t: 2*inter >= union (union>0 always)
    int ig = 0;
    #pragma unroll
    for (int i = 0; i < 13; ++i) {
        const int box = i * 4 + s;
        if (box < NT) {
            float iw = fminf(pmaxx, s_tmaxx[box]) - fmaxf(pminx, s_tminx[box]);
            float ih = fminf(pmaxy, s_tmaxy[box]) - fmaxf(pminy, s_tminy[box]);
            iw = fmaxf(iw, 0.0f);
            ih = fmaxf(ih, 0.0f);
            float inter = iw * ih;
            float uni   = parea + s_tarea[box] - inter;
            ig |= (2.0f * inter >= uni) ? 1 : 0;
        }
    }
    ig |= __shfl_xor(ig, 1);
    ig |= __shfl_xor(ig, 2);

    // ---- classes: lane s owns classes at idx=4j+s (j>=1; j>=2 for s==0;
    //      plus idx84 for s==0). 20 classes per lane, 2 online streams. ----
    float tm[2] = { -1e30f, -1e30f }, pa[2] = { 0.0f, 0.0f };
    float mm[2] = { -1e30f, -1e30f }, ss[2] = { 0.0f, 0.0f };

    #pragma unroll
    for (int j = 1; j <= 21; ++j) {
        const int k = j & 1;
        float tc, pc;
        bool valid;
        if (j < 21) { valid = (j >= 2) || (s != 0); tc = tv[j]; pc = pv[j]; }
        else        { valid = (s == 0);             tc = t84;   pc = p84;   }
        const float tcm = valid ? tc : -1e30f;
        const float pcm = valid ? pc : -1e30f;
        const bool upd = tcm > tm[k];
        tm[k] = upd ? tcm : tm[k];
        pa[k] = upd ? pc  : pa[k];
        const float mn = fmaxf(mm[k], pcm);
        ss[k] = ss[k] * __expf(mm[k] - mn) + __expf(pcm - mn);
        mm[k] = mn;
    }
    // combine the 2 streams
    float tmax = tm[0], p_at = pa[0];
    {
        const bool upd = tm[1] > tmax;
        tmax = upd ? tm[1] : tmax;
        p_at = upd ? pa[1] : p_at;
    }
    float m  = fmaxf(mm[0], mm[1]);
    float sv = ss[0] * __expf(mm[0] - m) + ss[1] * __expf(mm[1] - m);
    // combine across the 4 lanes (butterfly)
    #pragma unroll
    for (int d = 1; d <= 2; d <<= 1) {
        const float om_ = __shfl_xor(m, d);
        const float os_ = __shfl_xor(sv, d);
        const float mn  = fmaxf(m, om_);
        sv = sv * __expf(m - mn) + os_ * __expf(om_ - mn);
        m  = mn;
        const float ot = __shfl_xor(tmax, d);
        const float op = __shfl_xor(p_at, d);
        const bool upd = ot > tmax;
        tmax = upd ? ot : tmax;
        p_at = upd ? op : p_at;
    }
    const float ce = (m + __logf(sv)) - p_at;

    // ---- deltas (lane s==0 emits the cell's partial) ----
    const float om  = t4;
    const float ew  = __expf(t2) * aw * (1.0f / 512.0f);
    const float eh  = __expf(t3) * ah * (1.0f / 512.0f);
    const float whs = 2.0f - ew * eh;

    const float xyd0 = om * (predx - t0) * whs;
    const float xyd1 = om * (predy - t1) * whs;
    const float whd0 = om * (p2 - t2) * whs;
    const float whd1 = om * (p3 - t3) * whs;
    const float cd   = om * (pconf - t4) * 5.0f + (1.0f - om) * (ig ? 0.0f : pconf);

    float partial = xyd0 * xyd0 + xyd1 * xyd1 + whd0 * whd0 + whd1 * whd1 +
                    cd * cd + om * ce;
    partial = (s == 0) ? partial : 0.0f;

    // ---- wave + block reduction, one atomic per block ----
    #pragma unroll
    for (int off = 32; off > 0; off >>= 1)
        partial += __shfl_down(partial, off);

    const int wid = threadIdx.x >> 6;
    if (lane == 0) s_red[wid] = partial;
    __syncthreads();
    if (threadIdx.x == 0)
        atomicAdd(&out[b], s_red[0] + s_red[1] + s_red[2] + s_red[3]);
}

extern "C" void kernel_launch(void* const* d_in, const int* in_sizes, int n_in,
                              void* d_out, int out_size, void* d_ws, size_t ws_size,
                              hipStream_t stream) {
    // setup_inputs order: input_image (unused), y_pred, y_true, true_boxes, anchors
    const float* y_pred     = (const float*)d_in[1];
    const float* y_true     = (const float*)d_in[2];
    const float* true_boxes = (const float*)d_in[3];
    const float* anchors    = (const float*)d_in[4];
    float* out = (float*)d_out;

    hipMemsetAsync(d_out, 0, (size_t)out_size * sizeof(float), stream);

    dim3 grid(294912 / 64);   // 4608 blocks, 64 cells each
    yolo_loss_kernel<<<grid, 256, 0, stream>>>(y_pred, y_true, true_boxes, anchors, out);
}